// Round 2
// baseline (346.336 us; speedup 1.0000x reference)
//
#include <hip/hip_runtime.h>
#include <math.h>

// (B,H,W,T,C) = (4,200,200,5,64), fp32 in/out.
constexpr int Bn = 4, Hn = 200, Wn = 200, Tn = 5, Cn = 64;
constexpr int C4 = Cn / 4;                   // 16 float4 per (pixel,t)
constexpr int PIXELS = Bn * Hn * Wn;         // 160,000
constexpr int PPB = 16;                      // pixels per block
constexpr int BLOCK = PPB * C4;              // 256 threads
constexpr int PIX_STRIDE4 = Tn * C4;         // 80 float4 per pixel block
constexpr int NBLK = PIXELS / PPB;           // 10,000 blocks
constexpr int NXCD = 8;
constexpr int CHUNK = NBLK / NXCD;           // 1250 (exact: 10000 % 8 == 0 -> bijective)

// Native clang vector type — required by __builtin_nontemporal_* (HIP's
// float4 is a class and is rejected). Same 16-B layout/alignment.
typedef float f4 __attribute__((ext_vector_type(4)));

__global__ __launch_bounds__(BLOCK) void tf_warp_kernel(
    const f4* __restrict__ in4,
    const float* __restrict__ ego,
    f4* __restrict__ out4)
{
    __shared__ int   s_base[PPB][4];   // f4-index of corner (y,x) pixel block
    __shared__ float s_wgt[PPB][4];    // bilinear weights with validity folded

    // XCD-aware swizzle: default dispatch round-robins blocks across the 8 XCDs,
    // so adjacent output rows (which share gathered input rows y0/y1) land on
    // different L2s. Remap so each XCD owns a contiguous range of blocks.
    const int raw = blockIdx.x;
    const int bid = (raw % NXCD) * CHUNK + raw / NXCD;

    const int tid  = threadIdx.x;
    const int pos0 = bid * PPB;

    if (tid < PPB) {
        int pos = pos0 + tid;          // (b*H + h)*W + w
        int w   = pos % Wn;
        int bh  = pos / Wn;
        int h   = bh % Hn;
        int b   = bh / Hn;

        float dxn  = ego[b * 3 + 0] * 0.01f;   // / (MAP_RANGE/2 = 100)
        float dyn  = ego[b * 3 + 1] * 0.01f;
        float dyaw = ego[b * 3 + 2];
        float sth, cth;
        sincosf(dyaw, &sth, &cth);
        float tx = -(cth * dxn + sth * dyn);
        float ty =  sth * dxn - cth * dyn;

        float xs = (2.0f * (float)w + 1.0f) / (float)Wn - 1.0f;
        float ys = (2.0f * (float)h + 1.0f) / (float)Hn - 1.0f;

        float gx =  cth * xs + sth * ys + tx;
        float gy = -sth * xs + cth * ys + ty;

        float ix = ((gx + 1.0f) * (float)Wn - 1.0f) * 0.5f;
        float iy = ((gy + 1.0f) * (float)Hn - 1.0f) * 0.5f;

        float ix0f = floorf(ix), iy0f = floorf(iy);
        float wx1 = ix - ix0f, wx0 = 1.0f - wx1;
        float wy1 = iy - iy0f, wy0 = 1.0f - wy1;
        float ix1f = ix0f + 1.0f, iy1f = iy0f + 1.0f;

        bool vx0 = (ix0f >= 0.0f) && (ix0f <= (float)(Wn - 1));
        bool vx1 = (ix1f >= 0.0f) && (ix1f <= (float)(Wn - 1));
        bool vy0 = (iy0f >= 0.0f) && (iy0f <= (float)(Hn - 1));
        bool vy1 = (iy1f >= 0.0f) && (iy1f <= (float)(Hn - 1));

        int x0 = (int)fminf(fmaxf(ix0f, 0.0f), (float)(Wn - 1));
        int x1 = (int)fminf(fmaxf(ix1f, 0.0f), (float)(Wn - 1));
        int y0 = (int)fminf(fmaxf(iy0f, 0.0f), (float)(Hn - 1));
        int y1 = (int)fminf(fmaxf(iy1f, 0.0f), (float)(Hn - 1));

        int bH = b * Hn;
        s_base[tid][0] = ((bH + y0) * Wn + x0) * PIX_STRIDE4;
        s_base[tid][1] = ((bH + y0) * Wn + x1) * PIX_STRIDE4;
        s_base[tid][2] = ((bH + y1) * Wn + x0) * PIX_STRIDE4;
        s_base[tid][3] = ((bH + y1) * Wn + x1) * PIX_STRIDE4;
        s_wgt[tid][0]  = wy0 * wx0 * ((vy0 && vx0) ? 1.0f : 0.0f);
        s_wgt[tid][1]  = wy0 * wx1 * ((vy0 && vx1) ? 1.0f : 0.0f);
        s_wgt[tid][2]  = wy1 * wx0 * ((vy1 && vx0) ? 1.0f : 0.0f);
        s_wgt[tid][3]  = wy1 * wx1 * ((vy1 && vx1) ? 1.0f : 0.0f);
    }
    __syncthreads();

    const int p   = tid >> 4;          // local pixel 0..15
    const int c4  = tid & (C4 - 1);    // f4 lane within channel row
    const int pos = pos0 + p;
    const int obase = pos * PIX_STRIDE4 + c4;

    const int b00 = s_base[p][0] + c4;
    const int b01 = s_base[p][1] + c4;
    const int b10 = s_base[p][2] + c4;
    const int b11 = s_base[p][3] + c4;
    const float w00 = s_wgt[p][0];
    const float w01 = s_wgt[p][1];
    const float w10 = s_wgt[p][2];
    const float w11 = s_wgt[p][3];

    // Issue all 17 independent loads up front for max MLP.
    // Gather loads stay cacheable (L2/L3 reuse across neighboring pixels).
    f4 v00[4], v01[4], v10[4], v11[4];
#pragma unroll
    for (int t = 0; t < 4; ++t) {
        v00[t] = in4[b00 + t * C4];
        v01[t] = in4[b01 + t * C4];
        v10[t] = in4[b10 + t * C4];
        v11[t] = in4[b11 + t * C4];
    }
    // Current frame (t = T-1) is read exactly once and never gathered: NT load.
    f4 cur = __builtin_nontemporal_load(&in4[obase + 4 * C4]);

#pragma unroll
    for (int t = 0; t < 4; ++t) {
        f4 o = w00 * v00[t] + w01 * v01[t] + w10 * v10[t] + w11 * v11[t];
        // Output is write-once / never re-read: non-temporal store keeps the
        // 256 MB L3 free for the 204.8 MB input so gather re-reads hit L3.
        __builtin_nontemporal_store(o, &out4[obase + t * C4]);
    }
    __builtin_nontemporal_store(cur, &out4[obase + 4 * C4]);
}

extern "C" void kernel_launch(void* const* d_in, const int* in_sizes, int n_in,
                              void* d_out, int out_size, void* d_ws, size_t ws_size,
                              hipStream_t stream) {
    const f4* in4 = (const f4*)d_in[0];
    const float* ego = (const float*)d_in[1];
    f4* out4 = (f4*)d_out;

    tf_warp_kernel<<<NBLK, BLOCK, 0, stream>>>(in4, ego, out4);
}